// Round 2
// baseline (3200.228 us; speedup 1.0000x reference)
//
#include <hip/hip_runtime.h>

#define NN 20000
#define NE 320000
#define D 128
#define LAYERS 3
#define BN_EPS 1e-5f

__device__ __forceinline__ float sigm_(float x) { return 1.0f / (1.0f + __expf(-x)); }
__device__ __forceinline__ float silu_(float x) { return x * sigm_(x); }
__device__ __forceinline__ float bf2f(unsigned short u) {
    union { unsigned int u; float f; } v; v.u = ((unsigned int)u) << 16; return v.f;
}
__device__ __forceinline__ unsigned short f2bf(float f) {
    union { float f; unsigned int u; } v; v.f = f;
    return (unsigned short)((v.u + 0x7FFFu + ((v.u >> 16) & 1u)) >> 16);
}

struct Mats { const float* W[4]; const float* b[4]; float* C[4]; };

// ---------- node matmul: C[y][N,128] = h @ W[y] + b[y], fp32 in/out, 4 mats via blockIdx.y
__global__ __launch_bounds__(256, 2) void mm_node_kernel(
    const float* __restrict__ A, int M, Mats ms)
{
    __shared__ float sA[32][132];  // [k][m]
    __shared__ float sW[32][132];  // [k][c]
    const int mat = blockIdx.y;
    const float* __restrict__ W = ms.W[mat];
    const float* __restrict__ bias = ms.b[mat];
    float* __restrict__ C = ms.C[mat];
    const int row0 = blockIdx.x * 128;
    const int t = threadIdx.x;
    const int ry = t >> 4, cx = t & 15;
    const int m0 = ry * 8, c0 = cx * 8;

    float acc[8][8];
#pragma unroll
    for (int i = 0; i < 8; ++i)
#pragma unroll
        for (int j = 0; j < 8; ++j) acc[i][j] = 0.f;

    const int lm = t >> 3;
    const int lk4 = (t & 7) * 4;
    const int wk = t >> 5;
    const int wc4 = (t & 31) * 4;

    for (int kk = 0; kk < 128; kk += 32) {
        __syncthreads();
#pragma unroll
        for (int i = 0; i < 4; ++i) {
            int m = lm + i * 32;
            int gr = row0 + m;
            float4 v = make_float4(0.f, 0.f, 0.f, 0.f);
            if (gr < M) v = *(const float4*)(A + (size_t)gr * D + kk + lk4);
            sA[lk4 + 0][m] = v.x; sA[lk4 + 1][m] = v.y;
            sA[lk4 + 2][m] = v.z; sA[lk4 + 3][m] = v.w;
        }
#pragma unroll
        for (int i = 0; i < 4; ++i) {
            int k = wk + i * 8;
            *(float4*)&sW[k][wc4] = *(const float4*)(W + (size_t)(kk + k) * D + wc4);
        }
        __syncthreads();
#pragma unroll
        for (int k = 0; k < 32; ++k) {
            float a[8], w[8];
            *(float4*)&a[0] = *(const float4*)&sA[k][m0];
            *(float4*)&a[4] = *(const float4*)&sA[k][m0 + 4];
            *(float4*)&w[0] = *(const float4*)&sW[k][c0];
            *(float4*)&w[4] = *(const float4*)&sW[k][c0 + 4];
#pragma unroll
            for (int i = 0; i < 8; ++i)
#pragma unroll
                for (int j = 0; j < 8; ++j) acc[i][j] = fmaf(a[i], w[j], acc[i][j]);
        }
    }

    float bs[8];
#pragma unroll
    for (int j = 0; j < 8; ++j) bs[j] = bias[c0 + j];

#pragma unroll
    for (int i = 0; i < 8; ++i) {
        int gr = row0 + m0 + i;
        if (gr >= M) break;
        float v[8];
#pragma unroll
        for (int j = 0; j < 8; ++j) v[j] = acc[i][j] + bs[j];
        *(float4*)(C + (size_t)gr * D + c0) = *(float4*)&v[0];
        *(float4*)(C + (size_t)gr * D + c0 + 4) = *(float4*)&v[4];
    }
}

// ---------- edge matmul: bf16 A -> EPI 0: bf16 store; 1: silu bf16 store; 2: fused f2+f3 -> fp32 out
template <int EPI>
__global__ __launch_bounds__(256, 2) void mm_edge_kernel(
    const unsigned short* __restrict__ A, int M,
    const float* __restrict__ W, const float* __restrict__ bias,
    unsigned short* __restrict__ Cb,
    const float* __restrict__ f3w, const float* __restrict__ f3b,
    float* __restrict__ out)
{
    __shared__ float sA[32][132];
    __shared__ float sW[32][132];
    const int row0 = blockIdx.x * 128;
    const int t = threadIdx.x;
    const int ry = t >> 4, cx = t & 15;
    const int m0 = ry * 8, c0 = cx * 8;

    float acc[8][8];
#pragma unroll
    for (int i = 0; i < 8; ++i)
#pragma unroll
        for (int j = 0; j < 8; ++j) acc[i][j] = 0.f;

    const int lm = t >> 3;
    const int lk4 = (t & 7) * 4;
    const int wk = t >> 5;
    const int wc4 = (t & 31) * 4;

    for (int kk = 0; kk < 128; kk += 32) {
        __syncthreads();
#pragma unroll
        for (int i = 0; i < 4; ++i) {
            int m = lm + i * 32;
            int gr = row0 + m;
            ushort4 v = make_ushort4(0, 0, 0, 0);
            if (gr < M) v = *(const ushort4*)(A + (size_t)gr * D + kk + lk4);
            sA[lk4 + 0][m] = bf2f(v.x); sA[lk4 + 1][m] = bf2f(v.y);
            sA[lk4 + 2][m] = bf2f(v.z); sA[lk4 + 3][m] = bf2f(v.w);
        }
#pragma unroll
        for (int i = 0; i < 4; ++i) {
            int k = wk + i * 8;
            *(float4*)&sW[k][wc4] = *(const float4*)(W + (size_t)(kk + k) * D + wc4);
        }
        __syncthreads();
#pragma unroll
        for (int k = 0; k < 32; ++k) {
            float a[8], w[8];
            *(float4*)&a[0] = *(const float4*)&sA[k][m0];
            *(float4*)&a[4] = *(const float4*)&sA[k][m0 + 4];
            *(float4*)&w[0] = *(const float4*)&sW[k][c0];
            *(float4*)&w[4] = *(const float4*)&sW[k][c0 + 4];
#pragma unroll
            for (int i = 0; i < 8; ++i)
#pragma unroll
                for (int j = 0; j < 8; ++j) acc[i][j] = fmaf(a[i], w[j], acc[i][j]);
        }
    }

    float bs[8];
#pragma unroll
    for (int j = 0; j < 8; ++j) bs[j] = bias[c0 + j];

    if (EPI == 2) {
        float f3[8];
#pragma unroll
        for (int j = 0; j < 8; ++j) f3[j] = f3w[c0 + j];
        float part[8];
#pragma unroll
        for (int i = 0; i < 8; ++i) {
            float s = 0.f;
#pragma unroll
            for (int j = 0; j < 8; ++j) s = fmaf(silu_(acc[i][j] + bs[j]), f3[j], s);
            part[i] = s;
        }
        __syncthreads();
        float* red = &sA[0][0];  // reuse as [128][17]
#pragma unroll
        for (int i = 0; i < 8; ++i) red[(m0 + i) * 17 + cx] = part[i];
        __syncthreads();
        if (t < 128 && row0 + t < M) {
            float s = 0.f;
#pragma unroll
            for (int x = 0; x < 16; ++x) s += red[t * 17 + x];
            out[row0 + t] = sigm_(s + f3b[0]);
        }
        return;
    }

#pragma unroll
    for (int i = 0; i < 8; ++i) {
        int gr = row0 + m0 + i;
        if (gr >= M) break;
        ushort4 v0, v1;
        float x0 = acc[i][0] + bs[0], x1 = acc[i][1] + bs[1];
        float x2 = acc[i][2] + bs[2], x3 = acc[i][3] + bs[3];
        float x4 = acc[i][4] + bs[4], x5 = acc[i][5] + bs[5];
        float x6 = acc[i][6] + bs[6], x7 = acc[i][7] + bs[7];
        if (EPI == 1) {
            x0 = silu_(x0); x1 = silu_(x1); x2 = silu_(x2); x3 = silu_(x3);
            x4 = silu_(x4); x5 = silu_(x5); x6 = silu_(x6); x7 = silu_(x7);
        }
        v0 = make_ushort4(f2bf(x0), f2bf(x1), f2bf(x2), f2bf(x3));
        v1 = make_ushort4(f2bf(x4), f2bf(x5), f2bf(x6), f2bf(x7));
        *(ushort4*)(Cb + (size_t)gr * D + c0) = v0;
        *(ushort4*)(Cb + (size_t)gr * D + c0 + 4) = v1;
    }
}

// ---------- input projections
__global__ __launch_bounds__(256) void init_h_kernel(
    const float* __restrict__ x, const float* __restrict__ hp_w,
    const float* __restrict__ hp_b, float* __restrict__ h)
{
    int idx = blockIdx.x * 256 + threadIdx.x;
    int n = idx >> 5, d = (idx & 31) * 4;
    if (n >= NN) return;
    float x0 = x[n * 2], x1 = x[n * 2 + 1];
    float4 w0 = *(const float4*)(hp_w + d);
    float4 w1 = *(const float4*)(hp_w + D + d);
    float4 b = *(const float4*)(hp_b + d);
    float4 o;
    o.x = silu_(fmaf(x0, w0.x, fmaf(x1, w1.x, b.x)));
    o.y = silu_(fmaf(x0, w0.y, fmaf(x1, w1.y, b.y)));
    o.z = silu_(fmaf(x0, w0.z, fmaf(x1, w1.z, b.z)));
    o.w = silu_(fmaf(x0, w0.w, fmaf(x1, w1.w, b.w)));
    *(float4*)(h + (size_t)n * D + d) = o;
}

__global__ __launch_bounds__(256) void init_e_kernel(
    const float* __restrict__ ea, const float* __restrict__ ep_w,
    const float* __restrict__ ep_b, unsigned short* __restrict__ e)
{
    int idx = blockIdx.x * 256 + threadIdx.x;
    int i = idx >> 5, d = (idx & 31) * 4;
    if (i >= NE) return;
    float a = ea[i];
    float4 w = *(const float4*)(ep_w + d);
    float4 b = *(const float4*)(ep_b + d);
    ushort4 o;
    o.x = f2bf(silu_(fmaf(a, w.x, b.x)));
    o.y = f2bf(silu_(fmaf(a, w.y, b.y)));
    o.z = f2bf(silu_(fmaf(a, w.z, b.z)));
    o.w = f2bf(silu_(fmaf(a, w.w, b.w)));
    *(ushort4*)(e + (size_t)i * D + d) = o;
}

__global__ __launch_bounds__(256) void cnt_kernel(const int* __restrict__ src, float* __restrict__ cnt)
{
    int i = blockIdx.x * 256 + threadIdx.x;
    if (i < NE) atomicAdd(&cnt[src[i]], 1.0f);
}

__global__ __launch_bounds__(256) void inv_kernel(float* __restrict__ cnt)
{
    int n = blockIdx.x * 256 + threadIdx.x;
    if (n < NN) cnt[n] = 1.0f / fmaxf(cnt[n], 1.0f);
}

// scatter sigmoid(e)*Vh[dst]*inv_cnt[src] into Uh (which holds h@Uw+Ub) -> becomes t_h
__global__ __launch_bounds__(256) void scatter_kernel(
    const unsigned short* __restrict__ e, const float* __restrict__ Vh,
    const int* __restrict__ src, const int* __restrict__ dst,
    const float* __restrict__ inv_cnt, float* __restrict__ Uh)
{
    int idx = blockIdx.x * 256 + threadIdx.x;
    int i = idx >> 5, d = (idx & 31) * 4;
    if (i >= NE) return;
    int s = src[i], g = dst[i];
    float ic = inv_cnt[s];
    ushort4 ev = *(const ushort4*)(e + (size_t)i * D + d);
    float4 vv = *(const float4*)(Vh + (size_t)g * D + d);
    float* ap = Uh + (size_t)s * D + d;
    atomicAdd(ap + 0, sigm_(bf2f(ev.x)) * vv.x * ic);
    atomicAdd(ap + 1, sigm_(bf2f(ev.y)) * vv.y * ic);
    atomicAdd(ap + 2, sigm_(bf2f(ev.z)) * vv.z * ic);
    atomicAdd(ap + 3, sigm_(bf2f(ev.w)) * vv.w * ic);
}

// column stats (sum, sumsq) of fp32 t_h
__global__ __launch_bounds__(256) void colstats_h_kernel(
    const float* __restrict__ Th, float* __restrict__ stats)
{
    __shared__ float red1[8][128], red2[8][128];
    int t = threadIdx.x;
    int c0 = (t & 31) * 4, half = t >> 5;
    int rbase = blockIdx.x * 1024;
    float s1[4] = {0, 0, 0, 0}, s2[4] = {0, 0, 0, 0};
    for (int i = 0; i < 128; ++i) {
        int r = rbase + half + 8 * i;
        if (r >= NN) break;
        float4 v = *(const float4*)(Th + (size_t)r * D + c0);
        s1[0] += v.x; s2[0] = fmaf(v.x, v.x, s2[0]);
        s1[1] += v.y; s2[1] = fmaf(v.y, v.y, s2[1]);
        s1[2] += v.z; s2[2] = fmaf(v.z, v.z, s2[2]);
        s1[3] += v.w; s2[3] = fmaf(v.w, v.w, s2[3]);
    }
#pragma unroll
    for (int j = 0; j < 4; ++j) { red1[half][c0 + j] = s1[j]; red2[half][c0 + j] = s2[j]; }
    __syncthreads();
    if (t < 128) {
        float a = 0.f, b = 0.f;
#pragma unroll
        for (int hh = 0; hh < 8; ++hh) { a += red1[hh][t]; b += red2[hh][t]; }
        atomicAdd(stats + t, a);
        atomicAdd(stats + D + t, b);
    }
}

// t_e = Ae + Bh[src] + Ch[dst] in-place over bf16 T, column stats
__global__ __launch_bounds__(256) void colstats_e_kernel(
    unsigned short* __restrict__ T, const float* __restrict__ Bh, const float* __restrict__ Ch,
    const int* __restrict__ src, const int* __restrict__ dst, float* __restrict__ stats)
{
    __shared__ float red1[8][128], red2[8][128];
    int t = threadIdx.x;
    int c0 = (t & 31) * 4, half = t >> 5;
    int rbase = blockIdx.x * 1024;
    float s1[4] = {0, 0, 0, 0}, s2[4] = {0, 0, 0, 0};
    for (int i = 0; i < 128; ++i) {
        int r = rbase + half + 8 * i;
        if (r >= NE) break;
        int sr = src[r], dr = dst[r];
        ushort4 av = *(const ushort4*)(T + (size_t)r * D + c0);
        float4 bv = *(const float4*)(Bh + (size_t)sr * D + c0);
        float4 cv = *(const float4*)(Ch + (size_t)dr * D + c0);
        float t0 = bf2f(av.x) + bv.x + cv.x;
        float t1 = bf2f(av.y) + bv.y + cv.y;
        float t2 = bf2f(av.z) + bv.z + cv.z;
        float t3 = bf2f(av.w) + bv.w + cv.w;
        *(ushort4*)(T + (size_t)r * D + c0) = make_ushort4(f2bf(t0), f2bf(t1), f2bf(t2), f2bf(t3));
        s1[0] += t0; s2[0] = fmaf(t0, t0, s2[0]);
        s1[1] += t1; s2[1] = fmaf(t1, t1, s2[1]);
        s1[2] += t2; s2[2] = fmaf(t2, t2, s2[2]);
        s1[3] += t3; s2[3] = fmaf(t3, t3, s2[3]);
    }
#pragma unroll
    for (int j = 0; j < 4; ++j) { red1[half][c0 + j] = s1[j]; red2[half][c0 + j] = s2[j]; }
    __syncthreads();
    if (t < 128) {
        float a = 0.f, b = 0.f;
#pragma unroll
        for (int hh = 0; hh < 8; ++hh) { a += red1[hh][t]; b += red2[hh][t]; }
        atomicAdd(stats + t, a);
        atomicAdd(stats + D + t, b);
    }
}

__global__ void finalize_kernel(float* __restrict__ stats, const float* __restrict__ gamma,
                                const float* __restrict__ beta, float inv_rows)
{
    int c = threadIdx.x;  // 128
    float m = stats[c] * inv_rows;
    float v = stats[D + c] * inv_rows - m * m;
    float rstd = rsqrtf(v + BN_EPS);
    float sc = gamma[c] * rstd;
    stats[2 * D + c] = sc;
    stats[3 * D + c] = beta[c] - m * sc;
}

__global__ __launch_bounds__(256) void apply_h_kernel(
    float* __restrict__ h, const float* __restrict__ Th, const float* __restrict__ stats)
{
    int idx = blockIdx.x * 256 + threadIdx.x;
    int r = idx >> 5, d = (idx & 31) * 4;
    if (r >= NN) return;
    float4 tv = *(const float4*)(Th + (size_t)r * D + d);
    float4 sc = *(const float4*)(stats + 2 * D + d);
    float4 sh = *(const float4*)(stats + 3 * D + d);
    float4 hv = *(const float4*)(h + (size_t)r * D + d);
    hv.x += silu_(fmaf(tv.x, sc.x, sh.x));
    hv.y += silu_(fmaf(tv.y, sc.y, sh.y));
    hv.z += silu_(fmaf(tv.z, sc.z, sh.z));
    hv.w += silu_(fmaf(tv.w, sc.w, sh.w));
    *(float4*)(h + (size_t)r * D + d) = hv;
}

__global__ __launch_bounds__(256) void apply_e_kernel(
    unsigned short* __restrict__ e, const unsigned short* __restrict__ T,
    const float* __restrict__ stats)
{
    int idx = blockIdx.x * 256 + threadIdx.x;
    int r = idx >> 5, d = (idx & 31) * 4;
    if (r >= NE) return;
    ushort4 tv = *(const ushort4*)(T + (size_t)r * D + d);
    ushort4 ev = *(const ushort4*)(e + (size_t)r * D + d);
    float4 sc = *(const float4*)(stats + 2 * D + d);
    float4 sh = *(const float4*)(stats + 3 * D + d);
    ushort4 o;
    o.x = f2bf(bf2f(ev.x) + silu_(fmaf(bf2f(tv.x), sc.x, sh.x)));
    o.y = f2bf(bf2f(ev.y) + silu_(fmaf(bf2f(tv.y), sc.y, sh.y)));
    o.z = f2bf(bf2f(ev.z) + silu_(fmaf(bf2f(tv.z), sc.z, sh.z)));
    o.w = f2bf(bf2f(ev.w) + silu_(fmaf(bf2f(tv.w), sc.w, sh.w)));
    *(ushort4*)(e + (size_t)r * D + d) = o;
}

extern "C" void kernel_launch(void* const* d_in, const int* in_sizes, int n_in,
                              void* d_out, int out_size, void* d_ws, size_t ws_size,
                              hipStream_t stream)
{
    (void)in_sizes; (void)n_in; (void)out_size;
    const float* x = (const float*)d_in[0];
    const float* edge_attr = (const float*)d_in[1];
    const int* edge_index = (const int*)d_in[2];
    const int* src = edge_index;
    const int* dst = edge_index + NE;
    const float* hp_w = (const float*)d_in[3];
    const float* hp_b = (const float*)d_in[4];
    const float* ep_w = (const float*)d_in[5];
    const float* ep_b = (const float*)d_in[6];
    const float* Uw = (const float*)d_in[7];
    const float* Ub = (const float*)d_in[8];
    const float* Vw = (const float*)d_in[9];
    const float* Vb = (const float*)d_in[10];
    const float* Aw = (const float*)d_in[11];
    const float* Ab = (const float*)d_in[12];
    const float* Bw = (const float*)d_in[13];
    const float* Bb = (const float*)d_in[14];
    const float* Cw = (const float*)d_in[15];
    const float* Cb = (const float*)d_in[16];
    const float* h_gamma = (const float*)d_in[17];
    const float* h_beta = (const float*)d_in[18];
    const float* e_gamma = (const float*)d_in[19];
    const float* e_beta = (const float*)d_in[20];
    const float* f1w = (const float*)d_in[21];
    const float* f1b = (const float*)d_in[22];
    const float* f2w = (const float*)d_in[23];
    const float* f2b = (const float*)d_in[24];
    const float* f3w = (const float*)d_in[25];
    const float* f3b = (const float*)d_in[26];
    float* out = (float*)d_out;

    size_t off = 0;
    auto alloc = [&](size_t nbytes) {
        void* p = (char*)d_ws + off;
        off += ((nbytes + 255) / 256) * 256;
        return p;
    };
    unsigned short* e_bf = (unsigned short*)alloc((size_t)NE * D * 2);
    unsigned short* t_bf = (unsigned short*)alloc((size_t)NE * D * 2);
    float* h  = (float*)alloc((size_t)NN * D * 4);
    float* Uh = (float*)alloc((size_t)NN * D * 4);
    float* Vh = (float*)alloc((size_t)NN * D * 4);
    float* Bh = (float*)alloc((size_t)NN * D * 4);
    float* Ch = (float*)alloc((size_t)NN * D * 4);
    float* cnt = (float*)alloc(NN * 4);
    float* statsH = (float*)alloc(4 * D * 4);
    float* statsE = (float*)alloc(4 * D * 4);

    if (off > ws_size) return;  // diagnostic guard: fail w/ clean absmax instead of OOB fault

    const int nodeBlocks32 = (NN * 32 + 255) / 256;  // 2500
    const int edgeBlocks32 = (NE * 32) / 256;        // 40000
    const int nodeTiles = (NN + 127) / 128;          // 157
    const int edgeTiles = NE / 128;                  // 2500

    init_h_kernel<<<nodeBlocks32, 256, 0, stream>>>(x, hp_w, hp_b, h);
    init_e_kernel<<<edgeBlocks32, 256, 0, stream>>>(edge_attr, ep_w, ep_b, e_bf);

    hipMemsetAsync(cnt, 0, NN * sizeof(float), stream);
    cnt_kernel<<<NE / 256, 256, 0, stream>>>(src, cnt);
    inv_kernel<<<(NN + 255) / 256, 256, 0, stream>>>(cnt);

    for (int l = 0; l < LAYERS; ++l) {
        const size_t wl = (size_t)l * D * D;
        const size_t bl = (size_t)l * D;

        Mats m4;
        m4.W[0] = Uw + wl; m4.W[1] = Vw + wl; m4.W[2] = Bw + wl; m4.W[3] = Cw + wl;
        m4.b[0] = Ub + bl; m4.b[1] = Vb + bl; m4.b[2] = Bb + bl; m4.b[3] = Cb + bl;
        m4.C[0] = Uh; m4.C[1] = Vh; m4.C[2] = Bh; m4.C[3] = Ch;
        mm_node_kernel<<<dim3(nodeTiles, 4), 256, 0, stream>>>(h, NN, m4);

        // Ae -> t_bf (bf16)
        mm_edge_kernel<0><<<edgeTiles, 256, 0, stream>>>(e_bf, NE, Aw + wl, Ab + bl,
                                                         t_bf, nullptr, nullptr, nullptr);

        // aggregate into Uh => t_h
        scatter_kernel<<<edgeBlocks32, 256, 0, stream>>>(e_bf, Vh, src, dst, cnt, Uh);

        // h update
        hipMemsetAsync(statsH, 0, 2 * D * sizeof(float), stream);
        colstats_h_kernel<<<(NN + 1023) / 1024, 256, 0, stream>>>(Uh, statsH);
        finalize_kernel<<<1, D, 0, stream>>>(statsH, h_gamma + bl, h_beta + bl, 1.0f / NN);
        apply_h_kernel<<<nodeBlocks32, 256, 0, stream>>>(h, Uh, statsH);

        // e update
        hipMemsetAsync(statsE, 0, 2 * D * sizeof(float), stream);
        colstats_e_kernel<<<(NE + 1023) / 1024, 256, 0, stream>>>(t_bf, Bh, Ch, src, dst, statsE);
        finalize_kernel<<<1, D, 0, stream>>>(statsE, e_gamma + bl, e_beta + bl, 1.0f / NE);
        apply_e_kernel<<<edgeBlocks32, 256, 0, stream>>>(e_bf, t_bf, statsE);
    }

    // final MLP: z1 = silu(e@f1w+f1b) -> t_bf ; out = sigmoid(silu(z1@f2w+f2b)@f3w+f3b)
    mm_edge_kernel<1><<<edgeTiles, 256, 0, stream>>>(e_bf, NE, f1w, f1b,
                                                     t_bf, nullptr, nullptr, nullptr);
    mm_edge_kernel<2><<<edgeTiles, 256, 0, stream>>>(t_bf, NE, f2w, f2b,
                                                     nullptr, f3w, f3b, out);
}

// Round 3
// 1770.793 us; speedup vs baseline: 1.8072x; 1.8072x over previous
//
#include <hip/hip_runtime.h>

#define NN 20000
#define NE 320000
#define D 128
#define LAYERS 3
#define BN_EPS 1e-5f

__device__ __forceinline__ float sigm_(float x) { return 1.0f / (1.0f + __expf(-x)); }
__device__ __forceinline__ float silu_(float x) { return x * sigm_(x); }
__device__ __forceinline__ float bf2f(unsigned short u) {
    union { unsigned int u; float f; } v; v.u = ((unsigned int)u) << 16; return v.f;
}
__device__ __forceinline__ unsigned short f2bf(float f) {
    union { float f; unsigned int u; } v; v.f = f;
    return (unsigned short)((v.u + 0x7FFFu + ((v.u >> 16) & 1u)) >> 16);
}

struct Mats { const float* W[4]; const float* b[4]; float* C[4]; };

// ---------- node matmul: C[y][N,128] = h @ W[y] + b[y], fp32 in/out, 4 mats via blockIdx.y
__global__ __launch_bounds__(256, 2) void mm_node_kernel(
    const float* __restrict__ A, int M, Mats ms)
{
    __shared__ float sA[32][132];  // [k][m]
    __shared__ float sW[32][132];  // [k][c]
    const int mat = blockIdx.y;
    const float* __restrict__ W = ms.W[mat];
    const float* __restrict__ bias = ms.b[mat];
    float* __restrict__ C = ms.C[mat];
    const int row0 = blockIdx.x * 128;
    const int t = threadIdx.x;
    const int ry = t >> 4, cx = t & 15;
    const int m0 = ry * 8, c0 = cx * 8;

    float acc[8][8];
#pragma unroll
    for (int i = 0; i < 8; ++i)
#pragma unroll
        for (int j = 0; j < 8; ++j) acc[i][j] = 0.f;

    const int lm = t >> 3;
    const int lk4 = (t & 7) * 4;
    const int wk = t >> 5;
    const int wc4 = (t & 31) * 4;

    for (int kk = 0; kk < 128; kk += 32) {
        __syncthreads();
#pragma unroll
        for (int i = 0; i < 4; ++i) {
            int m = lm + i * 32;
            int gr = row0 + m;
            float4 v = make_float4(0.f, 0.f, 0.f, 0.f);
            if (gr < M) v = *(const float4*)(A + (size_t)gr * D + kk + lk4);
            sA[lk4 + 0][m] = v.x; sA[lk4 + 1][m] = v.y;
            sA[lk4 + 2][m] = v.z; sA[lk4 + 3][m] = v.w;
        }
#pragma unroll
        for (int i = 0; i < 4; ++i) {
            int k = wk + i * 8;
            *(float4*)&sW[k][wc4] = *(const float4*)(W + (size_t)(kk + k) * D + wc4);
        }
        __syncthreads();
#pragma unroll
        for (int k = 0; k < 32; ++k) {
            float a[8], w[8];
            *(float4*)&a[0] = *(const float4*)&sA[k][m0];
            *(float4*)&a[4] = *(const float4*)&sA[k][m0 + 4];
            *(float4*)&w[0] = *(const float4*)&sW[k][c0];
            *(float4*)&w[4] = *(const float4*)&sW[k][c0 + 4];
#pragma unroll
            for (int i = 0; i < 8; ++i)
#pragma unroll
                for (int j = 0; j < 8; ++j) acc[i][j] = fmaf(a[i], w[j], acc[i][j]);
        }
    }

    float bs[8];
#pragma unroll
    for (int j = 0; j < 8; ++j) bs[j] = bias[c0 + j];

#pragma unroll
    for (int i = 0; i < 8; ++i) {
        int gr = row0 + m0 + i;
        if (gr >= M) break;
        float v[8];
#pragma unroll
        for (int j = 0; j < 8; ++j) v[j] = acc[i][j] + bs[j];
        *(float4*)(C + (size_t)gr * D + c0) = *(float4*)&v[0];
        *(float4*)(C + (size_t)gr * D + c0 + 4) = *(float4*)&v[4];
    }
}

// ---------- edge matmul: bf16 A -> EPI 0: bf16 store; 1: silu bf16 store; 2: fused f2+f3 -> fp32 out
template <int EPI>
__global__ __launch_bounds__(256, 2) void mm_edge_kernel(
    const unsigned short* __restrict__ A, int M,
    const float* __restrict__ W, const float* __restrict__ bias,
    unsigned short* __restrict__ Cb,
    const float* __restrict__ f3w, const float* __restrict__ f3b,
    float* __restrict__ out)
{
    __shared__ float sA[32][132];
    __shared__ float sW[32][132];
    const int row0 = blockIdx.x * 128;
    const int t = threadIdx.x;
    const int ry = t >> 4, cx = t & 15;
    const int m0 = ry * 8, c0 = cx * 8;

    float acc[8][8];
#pragma unroll
    for (int i = 0; i < 8; ++i)
#pragma unroll
        for (int j = 0; j < 8; ++j) acc[i][j] = 0.f;

    const int lm = t >> 3;
    const int lk4 = (t & 7) * 4;
    const int wk = t >> 5;
    const int wc4 = (t & 31) * 4;

    for (int kk = 0; kk < 128; kk += 32) {
        __syncthreads();
#pragma unroll
        for (int i = 0; i < 4; ++i) {
            int m = lm + i * 32;
            int gr = row0 + m;
            ushort4 v = make_ushort4(0, 0, 0, 0);
            if (gr < M) v = *(const ushort4*)(A + (size_t)gr * D + kk + lk4);
            sA[lk4 + 0][m] = bf2f(v.x); sA[lk4 + 1][m] = bf2f(v.y);
            sA[lk4 + 2][m] = bf2f(v.z); sA[lk4 + 3][m] = bf2f(v.w);
        }
#pragma unroll
        for (int i = 0; i < 4; ++i) {
            int k = wk + i * 8;
            *(float4*)&sW[k][wc4] = *(const float4*)(W + (size_t)(kk + k) * D + wc4);
        }
        __syncthreads();
#pragma unroll
        for (int k = 0; k < 32; ++k) {
            float a[8], w[8];
            *(float4*)&a[0] = *(const float4*)&sA[k][m0];
            *(float4*)&a[4] = *(const float4*)&sA[k][m0 + 4];
            *(float4*)&w[0] = *(const float4*)&sW[k][c0];
            *(float4*)&w[4] = *(const float4*)&sW[k][c0 + 4];
#pragma unroll
            for (int i = 0; i < 8; ++i)
#pragma unroll
                for (int j = 0; j < 8; ++j) acc[i][j] = fmaf(a[i], w[j], acc[i][j]);
        }
    }

    float bs[8];
#pragma unroll
    for (int j = 0; j < 8; ++j) bs[j] = bias[c0 + j];

    if (EPI == 2) {
        float f3[8];
#pragma unroll
        for (int j = 0; j < 8; ++j) f3[j] = f3w[c0 + j];
        float part[8];
#pragma unroll
        for (int i = 0; i < 8; ++i) {
            float s = 0.f;
#pragma unroll
            for (int j = 0; j < 8; ++j) s = fmaf(silu_(acc[i][j] + bs[j]), f3[j], s);
            part[i] = s;
        }
        __syncthreads();
        float* red = &sA[0][0];  // reuse as [128][17]
#pragma unroll
        for (int i = 0; i < 8; ++i) red[(m0 + i) * 17 + cx] = part[i];
        __syncthreads();
        if (t < 128 && row0 + t < M) {
            float s = 0.f;
#pragma unroll
            for (int x = 0; x < 16; ++x) s += red[t * 17 + x];
            out[row0 + t] = sigm_(s + f3b[0]);
        }
        return;
    }

#pragma unroll
    for (int i = 0; i < 8; ++i) {
        int gr = row0 + m0 + i;
        if (gr >= M) break;
        ushort4 v0, v1;
        float x0 = acc[i][0] + bs[0], x1 = acc[i][1] + bs[1];
        float x2 = acc[i][2] + bs[2], x3 = acc[i][3] + bs[3];
        float x4 = acc[i][4] + bs[4], x5 = acc[i][5] + bs[5];
        float x6 = acc[i][6] + bs[6], x7 = acc[i][7] + bs[7];
        if (EPI == 1) {
            x0 = silu_(x0); x1 = silu_(x1); x2 = silu_(x2); x3 = silu_(x3);
            x4 = silu_(x4); x5 = silu_(x5); x6 = silu_(x6); x7 = silu_(x7);
        }
        v0 = make_ushort4(f2bf(x0), f2bf(x1), f2bf(x2), f2bf(x3));
        v1 = make_ushort4(f2bf(x4), f2bf(x5), f2bf(x6), f2bf(x7));
        *(ushort4*)(Cb + (size_t)gr * D + c0) = v0;
        *(ushort4*)(Cb + (size_t)gr * D + c0 + 4) = v1;
    }
}

// ---------- input projections
__global__ __launch_bounds__(256) void init_h_kernel(
    const float* __restrict__ x, const float* __restrict__ hp_w,
    const float* __restrict__ hp_b, float* __restrict__ h)
{
    int idx = blockIdx.x * 256 + threadIdx.x;
    int n = idx >> 5, d = (idx & 31) * 4;
    if (n >= NN) return;
    float x0 = x[n * 2], x1 = x[n * 2 + 1];
    float4 w0 = *(const float4*)(hp_w + d);
    float4 w1 = *(const float4*)(hp_w + D + d);
    float4 b = *(const float4*)(hp_b + d);
    float4 o;
    o.x = silu_(fmaf(x0, w0.x, fmaf(x1, w1.x, b.x)));
    o.y = silu_(fmaf(x0, w0.y, fmaf(x1, w1.y, b.y)));
    o.z = silu_(fmaf(x0, w0.z, fmaf(x1, w1.z, b.z)));
    o.w = silu_(fmaf(x0, w0.w, fmaf(x1, w1.w, b.w)));
    *(float4*)(h + (size_t)n * D + d) = o;
}

__global__ __launch_bounds__(256) void init_e_kernel(
    const float* __restrict__ ea, const float* __restrict__ ep_w,
    const float* __restrict__ ep_b, unsigned short* __restrict__ e)
{
    int idx = blockIdx.x * 256 + threadIdx.x;
    int i = idx >> 5, d = (idx & 31) * 4;
    if (i >= NE) return;
    float a = ea[i];
    float4 w = *(const float4*)(ep_w + d);
    float4 b = *(const float4*)(ep_b + d);
    ushort4 o;
    o.x = f2bf(silu_(fmaf(a, w.x, b.x)));
    o.y = f2bf(silu_(fmaf(a, w.y, b.y)));
    o.z = f2bf(silu_(fmaf(a, w.z, b.z)));
    o.w = f2bf(silu_(fmaf(a, w.w, b.w)));
    *(ushort4*)(e + (size_t)i * D + d) = o;
}

// ---------- CSR build (edge_index constant; rebuilt每 launch for graph-capture purity)
__global__ __launch_bounds__(256) void deg_kernel(const int* __restrict__ src, int* __restrict__ deg)
{
    int i = blockIdx.x * 256 + threadIdx.x;
    if (i < NE) atomicAdd(&deg[src[i]], 1);
}

// single-block scan: rowptr (exclusive) + inv_cnt
__global__ __launch_bounds__(256) void scan_kernel(
    const int* __restrict__ deg, int* __restrict__ rowptr, float* __restrict__ inv_cnt)
{
    __shared__ int chunk[256];
    const int t = threadIdx.x;
    const int CH = (NN + 255) / 256;  // 79
    int s = 0;
    for (int i = 0; i < CH; ++i) {
        int idx = t * CH + i;
        if (idx < NN) s += deg[idx];
    }
    chunk[t] = s;
    __syncthreads();
    for (int offs = 1; offs < 256; offs <<= 1) {
        int v = (t >= offs) ? chunk[t - offs] : 0;
        __syncthreads();
        chunk[t] += v;
        __syncthreads();
    }
    int base = (t == 0) ? 0 : chunk[t - 1];
    for (int i = 0; i < CH; ++i) {
        int idx = t * CH + i;
        if (idx < NN) {
            rowptr[idx] = base;
            int d = deg[idx];
            inv_cnt[idx] = 1.0f / fmaxf((float)d, 1.0f);
            base += d;
        }
    }
    if (t == 255) rowptr[NN] = base;
}

__global__ __launch_bounds__(256) void fill_kernel(
    const int* __restrict__ src, const int* __restrict__ rowptr,
    int* __restrict__ cursor, int* __restrict__ eidx)
{
    int i = blockIdx.x * 256 + threadIdx.x;
    if (i >= NE) return;
    int s = src[i];
    int p = atomicAdd(&cursor[s], 1);
    eidx[rowptr[s] + p] = i;
}

// ---------- gather aggregation: one wave per node; Uh += sum(sigm(e)*Vh[dst]) * inv_cnt  -> t_h
__global__ __launch_bounds__(256) void agg_kernel(
    const unsigned short* __restrict__ e, const float* __restrict__ Vh,
    const int* __restrict__ rowptr, const int* __restrict__ eidx,
    const int* __restrict__ dst, const float* __restrict__ inv_cnt,
    float* __restrict__ Uh)
{
    int n = blockIdx.x * 4 + (threadIdx.x >> 6);
    if (n >= NN) return;
    int lane = threadIdx.x & 63;
    int c2 = lane * 2;
    int beg = rowptr[n], end = rowptr[n + 1];
    float a0 = 0.f, a1 = 0.f;
    for (int j = beg; j < end; ++j) {
        int eid = eidx[j];
        int g = dst[eid];
        unsigned int ep = *(const unsigned int*)(e + (size_t)eid * D + c2);
        float2 vv = *(const float2*)(Vh + (size_t)g * D + c2);
        float e0 = bf2f((unsigned short)(ep & 0xffff));
        float e1 = bf2f((unsigned short)(ep >> 16));
        a0 = fmaf(sigm_(e0), vv.x, a0);
        a1 = fmaf(sigm_(e1), vv.y, a1);
    }
    float ic = inv_cnt[n];
    size_t o = (size_t)n * D + c2;
    float2 u = *(const float2*)(Uh + o);
    u.x = fmaf(a0, ic, u.x);
    u.y = fmaf(a1, ic, u.y);
    *(float2*)(Uh + o) = u;
}

// column stats (sum, sumsq) of fp32 t_h
__global__ __launch_bounds__(256) void colstats_h_kernel(
    const float* __restrict__ Th, float* __restrict__ stats)
{
    __shared__ float red1[8][128], red2[8][128];
    int t = threadIdx.x;
    int c0 = (t & 31) * 4, half = t >> 5;
    int rbase = blockIdx.x * 1024;
    float s1[4] = {0, 0, 0, 0}, s2[4] = {0, 0, 0, 0};
    for (int i = 0; i < 128; ++i) {
        int r = rbase + half + 8 * i;
        if (r >= NN) break;
        float4 v = *(const float4*)(Th + (size_t)r * D + c0);
        s1[0] += v.x; s2[0] = fmaf(v.x, v.x, s2[0]);
        s1[1] += v.y; s2[1] = fmaf(v.y, v.y, s2[1]);
        s1[2] += v.z; s2[2] = fmaf(v.z, v.z, s2[2]);
        s1[3] += v.w; s2[3] = fmaf(v.w, v.w, s2[3]);
    }
#pragma unroll
    for (int j = 0; j < 4; ++j) { red1[half][c0 + j] = s1[j]; red2[half][c0 + j] = s2[j]; }
    __syncthreads();
    if (t < 128) {
        float a = 0.f, b = 0.f;
#pragma unroll
        for (int hh = 0; hh < 8; ++hh) { a += red1[hh][t]; b += red2[hh][t]; }
        atomicAdd(stats + t, a);
        atomicAdd(stats + D + t, b);
    }
}

// t_e = Ae + Bh[src] + Ch[dst] in-place over bf16 T, column stats
__global__ __launch_bounds__(256) void colstats_e_kernel(
    unsigned short* __restrict__ T, const float* __restrict__ Bh, const float* __restrict__ Ch,
    const int* __restrict__ src, const int* __restrict__ dst, float* __restrict__ stats)
{
    __shared__ float red1[8][128], red2[8][128];
    int t = threadIdx.x;
    int c0 = (t & 31) * 4, half = t >> 5;
    int rbase = blockIdx.x * 1024;
    float s1[4] = {0, 0, 0, 0}, s2[4] = {0, 0, 0, 0};
    for (int i = 0; i < 128; ++i) {
        int r = rbase + half + 8 * i;
        if (r >= NE) break;
        int sr = src[r], dr = dst[r];
        ushort4 av = *(const ushort4*)(T + (size_t)r * D + c0);
        float4 bv = *(const float4*)(Bh + (size_t)sr * D + c0);
        float4 cv = *(const float4*)(Ch + (size_t)dr * D + c0);
        float t0 = bf2f(av.x) + bv.x + cv.x;
        float t1 = bf2f(av.y) + bv.y + cv.y;
        float t2 = bf2f(av.z) + bv.z + cv.z;
        float t3 = bf2f(av.w) + bv.w + cv.w;
        *(ushort4*)(T + (size_t)r * D + c0) = make_ushort4(f2bf(t0), f2bf(t1), f2bf(t2), f2bf(t3));
        s1[0] += t0; s2[0] = fmaf(t0, t0, s2[0]);
        s1[1] += t1; s2[1] = fmaf(t1, t1, s2[1]);
        s1[2] += t2; s2[2] = fmaf(t2, t2, s2[2]);
        s1[3] += t3; s2[3] = fmaf(t3, t3, s2[3]);
    }
#pragma unroll
    for (int j = 0; j < 4; ++j) { red1[half][c0 + j] = s1[j]; red2[half][c0 + j] = s2[j]; }
    __syncthreads();
    if (t < 128) {
        float a = 0.f, b = 0.f;
#pragma unroll
        for (int hh = 0; hh < 8; ++hh) { a += red1[hh][t]; b += red2[hh][t]; }
        atomicAdd(stats + t, a);
        atomicAdd(stats + D + t, b);
    }
}

__global__ void finalize_kernel(float* __restrict__ stats, const float* __restrict__ gamma,
                                const float* __restrict__ beta, float inv_rows)
{
    int c = threadIdx.x;  // 128
    float m = stats[c] * inv_rows;
    float v = stats[D + c] * inv_rows - m * m;
    float rstd = rsqrtf(v + BN_EPS);
    float sc = gamma[c] * rstd;
    stats[2 * D + c] = sc;
    stats[3 * D + c] = beta[c] - m * sc;
}

__global__ __launch_bounds__(256) void apply_h_kernel(
    float* __restrict__ h, const float* __restrict__ Th, const float* __restrict__ stats)
{
    int idx = blockIdx.x * 256 + threadIdx.x;
    int r = idx >> 5, d = (idx & 31) * 4;
    if (r >= NN) return;
    float4 tv = *(const float4*)(Th + (size_t)r * D + d);
    float4 sc = *(const float4*)(stats + 2 * D + d);
    float4 sh = *(const float4*)(stats + 3 * D + d);
    float4 hv = *(const float4*)(h + (size_t)r * D + d);
    hv.x += silu_(fmaf(tv.x, sc.x, sh.x));
    hv.y += silu_(fmaf(tv.y, sc.y, sh.y));
    hv.z += silu_(fmaf(tv.z, sc.z, sh.z));
    hv.w += silu_(fmaf(tv.w, sc.w, sh.w));
    *(float4*)(h + (size_t)r * D + d) = hv;
}

__global__ __launch_bounds__(256) void apply_e_kernel(
    unsigned short* __restrict__ e, const unsigned short* __restrict__ T,
    const float* __restrict__ stats)
{
    int idx = blockIdx.x * 256 + threadIdx.x;
    int r = idx >> 5, d = (idx & 31) * 4;
    if (r >= NE) return;
    ushort4 tv = *(const ushort4*)(T + (size_t)r * D + d);
    ushort4 ev = *(const ushort4*)(e + (size_t)r * D + d);
    float4 sc = *(const float4*)(stats + 2 * D + d);
    float4 sh = *(const float4*)(stats + 3 * D + d);
    ushort4 o;
    o.x = f2bf(bf2f(ev.x) + silu_(fmaf(bf2f(tv.x), sc.x, sh.x)));
    o.y = f2bf(bf2f(ev.y) + silu_(fmaf(bf2f(tv.y), sc.y, sh.y)));
    o.z = f2bf(bf2f(ev.z) + silu_(fmaf(bf2f(tv.z), sc.z, sh.z)));
    o.w = f2bf(bf2f(ev.w) + silu_(fmaf(bf2f(tv.w), sc.w, sh.w)));
    *(ushort4*)(e + (size_t)r * D + d) = o;
}

extern "C" void kernel_launch(void* const* d_in, const int* in_sizes, int n_in,
                              void* d_out, int out_size, void* d_ws, size_t ws_size,
                              hipStream_t stream)
{
    (void)in_sizes; (void)n_in; (void)out_size;
    const float* x = (const float*)d_in[0];
    const float* edge_attr = (const float*)d_in[1];
    const int* edge_index = (const int*)d_in[2];
    const int* src = edge_index;
    const int* dst = edge_index + NE;
    const float* hp_w = (const float*)d_in[3];
    const float* hp_b = (const float*)d_in[4];
    const float* ep_w = (const float*)d_in[5];
    const float* ep_b = (const float*)d_in[6];
    const float* Uw = (const float*)d_in[7];
    const float* Ub = (const float*)d_in[8];
    const float* Vw = (const float*)d_in[9];
    const float* Vb = (const float*)d_in[10];
    const float* Aw = (const float*)d_in[11];
    const float* Ab = (const float*)d_in[12];
    const float* Bw = (const float*)d_in[13];
    const float* Bb = (const float*)d_in[14];
    const float* Cw = (const float*)d_in[15];
    const float* Cb = (const float*)d_in[16];
    const float* h_gamma = (const float*)d_in[17];
    const float* h_beta = (const float*)d_in[18];
    const float* e_gamma = (const float*)d_in[19];
    const float* e_beta = (const float*)d_in[20];
    const float* f1w = (const float*)d_in[21];
    const float* f1b = (const float*)d_in[22];
    const float* f2w = (const float*)d_in[23];
    const float* f2b = (const float*)d_in[24];
    const float* f3w = (const float*)d_in[25];
    const float* f3b = (const float*)d_in[26];
    float* out = (float*)d_out;

    size_t off = 0;
    auto alloc = [&](size_t nbytes) {
        void* p = (char*)d_ws + off;
        off += ((nbytes + 255) / 256) * 256;
        return p;
    };
    unsigned short* e_bf = (unsigned short*)alloc((size_t)NE * D * 2);
    unsigned short* t_bf = (unsigned short*)alloc((size_t)NE * D * 2);
    float* h  = (float*)alloc((size_t)NN * D * 4);
    float* Uh = (float*)alloc((size_t)NN * D * 4);
    float* Vh = (float*)alloc((size_t)NN * D * 4);
    float* Bh = (float*)alloc((size_t)NN * D * 4);
    float* Ch = (float*)alloc((size_t)NN * D * 4);
    int* deg = (int*)alloc(NN * 4);
    int* rowptr = (int*)alloc((NN + 1) * 4);
    int* cursor = (int*)alloc(NN * 4);
    int* eidx = (int*)alloc((size_t)NE * 4);
    float* inv_cnt = (float*)alloc(NN * 4);
    float* statsH = (float*)alloc(4 * D * 4);
    float* statsE = (float*)alloc(4 * D * 4);

    if (off > ws_size) return;  // diagnostic guard

    const int nodeBlocks32 = (NN * 32 + 255) / 256;  // 2500
    const int edgeBlocks32 = (NE * 32) / 256;        // 40000
    const int nodeTiles = (NN + 127) / 128;          // 157
    const int edgeTiles = NE / 128;                  // 2500

    init_h_kernel<<<nodeBlocks32, 256, 0, stream>>>(x, hp_w, hp_b, h);
    init_e_kernel<<<edgeBlocks32, 256, 0, stream>>>(edge_attr, ep_w, ep_b, e_bf);

    // CSR build
    hipMemsetAsync(deg, 0, NN * sizeof(int), stream);
    hipMemsetAsync(cursor, 0, NN * sizeof(int), stream);
    deg_kernel<<<NE / 256, 256, 0, stream>>>(src, deg);
    scan_kernel<<<1, 256, 0, stream>>>(deg, rowptr, inv_cnt);
    fill_kernel<<<NE / 256, 256, 0, stream>>>(src, rowptr, cursor, eidx);

    for (int l = 0; l < LAYERS; ++l) {
        const size_t wl = (size_t)l * D * D;
        const size_t bl = (size_t)l * D;

        Mats m4;
        m4.W[0] = Uw + wl; m4.W[1] = Vw + wl; m4.W[2] = Bw + wl; m4.W[3] = Cw + wl;
        m4.b[0] = Ub + bl; m4.b[1] = Vb + bl; m4.b[2] = Bb + bl; m4.b[3] = Cb + bl;
        m4.C[0] = Uh; m4.C[1] = Vh; m4.C[2] = Bh; m4.C[3] = Ch;
        mm_node_kernel<<<dim3(nodeTiles, 4), 256, 0, stream>>>(h, NN, m4);

        // Ae -> t_bf (bf16)
        mm_edge_kernel<0><<<edgeTiles, 256, 0, stream>>>(e_bf, NE, Aw + wl, Ab + bl,
                                                         t_bf, nullptr, nullptr, nullptr);

        // gather-aggregate into Uh => t_h
        agg_kernel<<<(NN + 3) / 4, 256, 0, stream>>>(e_bf, Vh, rowptr, eidx, dst, inv_cnt, Uh);

        // h update
        hipMemsetAsync(statsH, 0, 2 * D * sizeof(float), stream);
        colstats_h_kernel<<<(NN + 1023) / 1024, 256, 0, stream>>>(Uh, statsH);
        finalize_kernel<<<1, D, 0, stream>>>(statsH, h_gamma + bl, h_beta + bl, 1.0f / NN);
        apply_h_kernel<<<nodeBlocks32, 256, 0, stream>>>(h, Uh, statsH);

        // e update
        hipMemsetAsync(statsE, 0, 2 * D * sizeof(float), stream);
        colstats_e_kernel<<<(NE + 1023) / 1024, 256, 0, stream>>>(t_bf, Bh, Ch, src, dst, statsE);
        finalize_kernel<<<1, D, 0, stream>>>(statsE, e_gamma + bl, e_beta + bl, 1.0f / NE);
        apply_e_kernel<<<edgeBlocks32, 256, 0, stream>>>(e_bf, t_bf, statsE);
    }

    // final MLP: z1 = silu(e@f1w+f1b) -> t_bf ; out = sigmoid(silu(z1@f2w+f2b)@f3w+f3b)
    mm_edge_kernel<1><<<edgeTiles, 256, 0, stream>>>(e_bf, NE, f1w, f1b,
                                                     t_bf, nullptr, nullptr, nullptr);
    mm_edge_kernel<2><<<edgeTiles, 256, 0, stream>>>(t_bf, NE, f2w, f2b,
                                                     nullptr, f3w, f3b, out);
}

// Round 4
// 1294.245 us; speedup vs baseline: 2.4727x; 1.3682x over previous
//
#include <hip/hip_runtime.h>

#define NN 20000
#define NE 320000
#define D 128
#define LAYERS 3
#define BN_EPS 1e-5f

typedef __attribute__((ext_vector_type(8))) short s16x8;
typedef __attribute__((ext_vector_type(4))) float f32x4;

__device__ __forceinline__ float sigm_(float x) { return 1.0f / (1.0f + __expf(-x)); }
__device__ __forceinline__ float silu_(float x) { return x * sigm_(x); }
__device__ __forceinline__ float bf2f(unsigned short u) {
    union { unsigned int u; float f; } v; v.u = ((unsigned int)u) << 16; return v.f;
}
__device__ __forceinline__ unsigned short f2bf(float f) {
    union { float f; unsigned int u; } v; v.f = f;
    return (unsigned short)((v.u + 0x7FFFu + ((v.u >> 16) & 1u)) >> 16);
}

struct Mats { const float* W[4]; const float* b[4]; float* C[4]; };

// ---------- node matmul: C[y][N,128] = h @ W[y] + b[y], fp32 in/out, 4 mats via blockIdx.y
__global__ __launch_bounds__(256, 2) void mm_node_kernel(
    const float* __restrict__ A, int M, Mats ms)
{
    __shared__ float sA[32][132];  // [k][m]
    __shared__ float sW[32][132];  // [k][c]
    const int mat = blockIdx.y;
    const float* __restrict__ W = ms.W[mat];
    const float* __restrict__ bias = ms.b[mat];
    float* __restrict__ C = ms.C[mat];
    const int row0 = blockIdx.x * 128;
    const int t = threadIdx.x;
    const int ry = t >> 4, cx = t & 15;
    const int m0 = ry * 8, c0 = cx * 8;

    float acc[8][8];
#pragma unroll
    for (int i = 0; i < 8; ++i)
#pragma unroll
        for (int j = 0; j < 8; ++j) acc[i][j] = 0.f;

    const int lm = t >> 3;
    const int lk4 = (t & 7) * 4;
    const int wk = t >> 5;
    const int wc4 = (t & 31) * 4;

    for (int kk = 0; kk < 128; kk += 32) {
        __syncthreads();
#pragma unroll
        for (int i = 0; i < 4; ++i) {
            int m = lm + i * 32;
            int gr = row0 + m;
            float4 v = make_float4(0.f, 0.f, 0.f, 0.f);
            if (gr < M) v = *(const float4*)(A + (size_t)gr * D + kk + lk4);
            sA[lk4 + 0][m] = v.x; sA[lk4 + 1][m] = v.y;
            sA[lk4 + 2][m] = v.z; sA[lk4 + 3][m] = v.w;
        }
#pragma unroll
        for (int i = 0; i < 4; ++i) {
            int k = wk + i * 8;
            *(float4*)&sW[k][wc4] = *(const float4*)(W + (size_t)(kk + k) * D + wc4);
        }
        __syncthreads();
#pragma unroll
        for (int k = 0; k < 32; ++k) {
            float a[8], w[8];
            *(float4*)&a[0] = *(const float4*)&sA[k][m0];
            *(float4*)&a[4] = *(const float4*)&sA[k][m0 + 4];
            *(float4*)&w[0] = *(const float4*)&sW[k][c0];
            *(float4*)&w[4] = *(const float4*)&sW[k][c0 + 4];
#pragma unroll
            for (int i = 0; i < 8; ++i)
#pragma unroll
                for (int j = 0; j < 8; ++j) acc[i][j] = fmaf(a[i], w[j], acc[i][j]);
        }
    }

    float bs[8];
#pragma unroll
    for (int j = 0; j < 8; ++j) bs[j] = bias[c0 + j];

#pragma unroll
    for (int i = 0; i < 8; ++i) {
        int gr = row0 + m0 + i;
        if (gr >= M) break;
        float v[8];
#pragma unroll
        for (int j = 0; j < 8; ++j) v[j] = acc[i][j] + bs[j];
        *(float4*)(C + (size_t)gr * D + c0) = *(float4*)&v[0];
        *(float4*)(C + (size_t)gr * D + c0 + 4) = *(float4*)&v[4];
    }
}

// ---------- weight convert: W fp32 [k][n] -> WT bf16 [n][k]
__global__ __launch_bounds__(256) void conv_wt_kernel(
    const float* __restrict__ W, unsigned short* __restrict__ WT)
{
    int idx = blockIdx.x * 256 + threadIdx.x;  // 16384
    int k = idx >> 7, n = idx & 127;
    WT[n * 128 + k] = f2bf(W[idx]);
}

// ---------- MFMA edge matmul: A bf16 [M,128] @ WT^T -> EPI 0: bf16 store; 1: silu bf16 store;
//            2: fused f2+f3 -> fp32 out.  M divisible by 128.
#define SWT_STRIDE 136
template <int EPI>
__global__ __launch_bounds__(256, 4) void mfmm_edge_kernel(
    const unsigned short* __restrict__ A,
    const unsigned short* __restrict__ WT,  // [n][k] bf16
    const float* __restrict__ bias,
    unsigned short* __restrict__ Cb,
    const float* __restrict__ f3w, const float* __restrict__ f3b,
    float* __restrict__ out)
{
    __shared__ unsigned short sW[128 * SWT_STRIDE];  // 34816 B; reused by epilogue
    const int t = threadIdx.x;
    const int w = t >> 6, lane = t & 63;
    const int q = lane >> 4, n = lane & 15;
    const int row0 = blockIdx.x * 128;

    // stage W^T (16384 bf16) padded to stride 136
#pragma unroll
    for (int i = 0; i < 8; ++i) {
        int flat = t * 8 + i * 2048;
        int r = flat >> 7, k = flat & 127;
        *(s16x8*)&sW[r * SWT_STRIDE + k] = *(const s16x8*)(WT + flat);
    }
    __syncthreads();

    f32x4 acc[2][8];
#pragma unroll
    for (int tm = 0; tm < 2; ++tm)
#pragma unroll
        for (int tc = 0; tc < 8; ++tc) acc[tm][tc] = (f32x4){0.f, 0.f, 0.f, 0.f};

    const unsigned short* a0p = A + (size_t)(row0 + w * 32 + n) * D + q * 8;

#pragma unroll
    for (int kk = 0; kk < 128; kk += 32) {
        s16x8 af0 = *(const s16x8*)(a0p + kk);
        s16x8 af1 = *(const s16x8*)(a0p + 16 * D + kk);
#pragma unroll
        for (int tc = 0; tc < 8; ++tc) {
            s16x8 bf = *(const s16x8*)&sW[(tc * 16 + n) * SWT_STRIDE + kk + q * 8];
            acc[0][tc] = __builtin_amdgcn_mfma_f32_16x16x32_bf16(af0, bf, acc[0][tc], 0, 0, 0);
            acc[1][tc] = __builtin_amdgcn_mfma_f32_16x16x32_bf16(af1, bf, acc[1][tc], 0, 0, 0);
        }
    }

    float bs[8];
#pragma unroll
    for (int tc = 0; tc < 8; ++tc) bs[tc] = bias[tc * 16 + n];

    if (EPI == 2) {
        float f3v[8];
#pragma unroll
        for (int tc = 0; tc < 8; ++tc) f3v[tc] = f3w[tc * 16 + n];
        __syncthreads();
        float* red = (float*)sW;  // [128][17]
#pragma unroll
        for (int tm = 0; tm < 2; ++tm)
#pragma unroll
            for (int r = 0; r < 4; ++r) {
                float p = 0.f;
#pragma unroll
                for (int tc = 0; tc < 8; ++tc)
                    p = fmaf(silu_(acc[tm][tc][r] + bs[tc]), f3v[tc], p);
                int row = w * 32 + tm * 16 + q * 4 + r;
                red[row * 17 + n] = p;
            }
        __syncthreads();
        if (t < 128) {
            float s = 0.f;
#pragma unroll
            for (int x = 0; x < 16; ++x) s += red[t * 17 + x];
            out[row0 + t] = sigm_(s + f3b[0]);
        }
        return;
    }

    __syncthreads();  // done reading sW
#pragma unroll
    for (int tm = 0; tm < 2; ++tm)
#pragma unroll
        for (int tc = 0; tc < 8; ++tc)
#pragma unroll
            for (int r = 0; r < 4; ++r) {
                int row = w * 32 + tm * 16 + q * 4 + r;
                int col = tc * 16 + n;
                float v = acc[tm][tc][r] + bs[tc];
                if (EPI == 1) v = silu_(v);
                sW[row * SWT_STRIDE + col] = f2bf(v);
            }
    __syncthreads();
#pragma unroll
    for (int i = 0; i < 8; ++i) {
        int row = (t >> 4) + i * 16;
        int col = (t & 15) * 8;
        s16x8 v = *(const s16x8*)&sW[row * SWT_STRIDE + col];
        *(s16x8*)(Cb + (size_t)(row0 + row) * D + col) = v;
    }
}

// ---------- input projections
__global__ __launch_bounds__(256) void init_h_kernel(
    const float* __restrict__ x, const float* __restrict__ hp_w,
    const float* __restrict__ hp_b, float* __restrict__ h)
{
    int idx = blockIdx.x * 256 + threadIdx.x;
    int n = idx >> 5, d = (idx & 31) * 4;
    if (n >= NN) return;
    float x0 = x[n * 2], x1 = x[n * 2 + 1];
    float4 w0 = *(const float4*)(hp_w + d);
    float4 w1 = *(const float4*)(hp_w + D + d);
    float4 b = *(const float4*)(hp_b + d);
    float4 o;
    o.x = silu_(fmaf(x0, w0.x, fmaf(x1, w1.x, b.x)));
    o.y = silu_(fmaf(x0, w0.y, fmaf(x1, w1.y, b.y)));
    o.z = silu_(fmaf(x0, w0.z, fmaf(x1, w1.z, b.z)));
    o.w = silu_(fmaf(x0, w0.w, fmaf(x1, w1.w, b.w)));
    *(float4*)(h + (size_t)n * D + d) = o;
}

__global__ __launch_bounds__(256) void init_e_kernel(
    const float* __restrict__ ea, const float* __restrict__ ep_w,
    const float* __restrict__ ep_b, unsigned short* __restrict__ e)
{
    int idx = blockIdx.x * 256 + threadIdx.x;
    int i = idx >> 5, d = (idx & 31) * 4;
    if (i >= NE) return;
    float a = ea[i];
    float4 w = *(const float4*)(ep_w + d);
    float4 b = *(const float4*)(ep_b + d);
    ushort4 o;
    o.x = f2bf(silu_(fmaf(a, w.x, b.x)));
    o.y = f2bf(silu_(fmaf(a, w.y, b.y)));
    o.z = f2bf(silu_(fmaf(a, w.z, b.z)));
    o.w = f2bf(silu_(fmaf(a, w.w, b.w)));
    *(ushort4*)(e + (size_t)i * D + d) = o;
}

// ---------- CSR build
__global__ __launch_bounds__(256) void deg_kernel(const int* __restrict__ src, int* __restrict__ deg)
{
    int i = blockIdx.x * 256 + threadIdx.x;
    if (i < NE) atomicAdd(&deg[src[i]], 1);
}

__global__ __launch_bounds__(256) void scan_kernel(
    const int* __restrict__ deg, int* __restrict__ rowptr, float* __restrict__ inv_cnt)
{
    __shared__ int chunk[256];
    const int t = threadIdx.x;
    const int CH = (NN + 255) / 256;
    int s = 0;
    for (int i = 0; i < CH; ++i) {
        int idx = t * CH + i;
        if (idx < NN) s += deg[idx];
    }
    chunk[t] = s;
    __syncthreads();
    for (int offs = 1; offs < 256; offs <<= 1) {
        int v = (t >= offs) ? chunk[t - offs] : 0;
        __syncthreads();
        chunk[t] += v;
        __syncthreads();
    }
    int base = (t == 0) ? 0 : chunk[t - 1];
    for (int i = 0; i < CH; ++i) {
        int idx = t * CH + i;
        if (idx < NN) {
            rowptr[idx] = base;
            int d = deg[idx];
            inv_cnt[idx] = 1.0f / fmaxf((float)d, 1.0f);
            base += d;
        }
    }
    if (t == 255) rowptr[NN] = base;
}

__global__ __launch_bounds__(256) void fill_kernel(
    const int* __restrict__ src, const int* __restrict__ rowptr,
    int* __restrict__ cursor, int* __restrict__ eidx)
{
    int i = blockIdx.x * 256 + threadIdx.x;
    if (i >= NE) return;
    int s = src[i];
    int p = atomicAdd(&cursor[s], 1);
    eidx[rowptr[s] + p] = i;
}

// ---------- gather aggregation
__global__ __launch_bounds__(256) void agg_kernel(
    const unsigned short* __restrict__ e, const float* __restrict__ Vh,
    const int* __restrict__ rowptr, const int* __restrict__ eidx,
    const int* __restrict__ dst, const float* __restrict__ inv_cnt,
    float* __restrict__ Uh)
{
    int n = blockIdx.x * 4 + (threadIdx.x >> 6);
    if (n >= NN) return;
    int lane = threadIdx.x & 63;
    int c2 = lane * 2;
    int beg = rowptr[n], end = rowptr[n + 1];
    float a0 = 0.f, a1 = 0.f;
    for (int j = beg; j < end; ++j) {
        int eid = eidx[j];
        int g = dst[eid];
        unsigned int ep = *(const unsigned int*)(e + (size_t)eid * D + c2);
        float2 vv = *(const float2*)(Vh + (size_t)g * D + c2);
        float e0 = bf2f((unsigned short)(ep & 0xffff));
        float e1 = bf2f((unsigned short)(ep >> 16));
        a0 = fmaf(sigm_(e0), vv.x, a0);
        a1 = fmaf(sigm_(e1), vv.y, a1);
    }
    float ic = inv_cnt[n];
    size_t o = (size_t)n * D + c2;
    float2 u = *(const float2*)(Uh + o);
    u.x = fmaf(a0, ic, u.x);
    u.y = fmaf(a1, ic, u.y);
    *(float2*)(Uh + o) = u;
}

// column stats (sum, sumsq) of fp32 t_h
__global__ __launch_bounds__(256) void colstats_h_kernel(
    const float* __restrict__ Th, float* __restrict__ stats)
{
    __shared__ float red1[8][128], red2[8][128];
    int t = threadIdx.x;
    int c0 = (t & 31) * 4, half = t >> 5;
    int rbase = blockIdx.x * 1024;
    float s1[4] = {0, 0, 0, 0}, s2[4] = {0, 0, 0, 0};
    for (int i = 0; i < 128; ++i) {
        int r = rbase + half + 8 * i;
        if (r >= NN) break;
        float4 v = *(const float4*)(Th + (size_t)r * D + c0);
        s1[0] += v.x; s2[0] = fmaf(v.x, v.x, s2[0]);
        s1[1] += v.y; s2[1] = fmaf(v.y, v.y, s2[1]);
        s1[2] += v.z; s2[2] = fmaf(v.z, v.z, s2[2]);
        s1[3] += v.w; s2[3] = fmaf(v.w, v.w, s2[3]);
    }
#pragma unroll
    for (int j = 0; j < 4; ++j) { red1[half][c0 + j] = s1[j]; red2[half][c0 + j] = s2[j]; }
    __syncthreads();
    if (t < 128) {
        float a = 0.f, b = 0.f;
#pragma unroll
        for (int hh = 0; hh < 8; ++hh) { a += red1[hh][t]; b += red2[hh][t]; }
        atomicAdd(stats + t, a);
        atomicAdd(stats + D + t, b);
    }
}

// t_e = Ae + Bh[src] + Ch[dst] in-place over bf16 T, column stats
__global__ __launch_bounds__(256) void colstats_e_kernel(
    unsigned short* __restrict__ T, const float* __restrict__ Bh, const float* __restrict__ Ch,
    const int* __restrict__ src, const int* __restrict__ dst, float* __restrict__ stats)
{
    __shared__ float red1[8][128], red2[8][128];
    int t = threadIdx.x;
    int c0 = (t & 31) * 4, half = t >> 5;
    int rbase = blockIdx.x * 1024;
    float s1[4] = {0, 0, 0, 0}, s2[4] = {0, 0, 0, 0};
    for (int i = 0; i < 128; ++i) {
        int r = rbase + half + 8 * i;
        if (r >= NE) break;
        int sr = src[r], dr = dst[r];
        ushort4 av = *(const ushort4*)(T + (size_t)r * D + c0);
        float4 bv = *(const float4*)(Bh + (size_t)sr * D + c0);
        float4 cv = *(const float4*)(Ch + (size_t)dr * D + c0);
        float t0 = bf2f(av.x) + bv.x + cv.x;
        float t1 = bf2f(av.y) + bv.y + cv.y;
        float t2 = bf2f(av.z) + bv.z + cv.z;
        float t3 = bf2f(av.w) + bv.w + cv.w;
        *(ushort4*)(T + (size_t)r * D + c0) = make_ushort4(f2bf(t0), f2bf(t1), f2bf(t2), f2bf(t3));
        s1[0] += t0; s2[0] = fmaf(t0, t0, s2[0]);
        s1[1] += t1; s2[1] = fmaf(t1, t1, s2[1]);
        s1[2] += t2; s2[2] = fmaf(t2, t2, s2[2]);
        s1[3] += t3; s2[3] = fmaf(t3, t3, s2[3]);
    }
#pragma unroll
    for (int j = 0; j < 4; ++j) { red1[half][c0 + j] = s1[j]; red2[half][c0 + j] = s2[j]; }
    __syncthreads();
    if (t < 128) {
        float a = 0.f, b = 0.f;
#pragma unroll
        for (int hh = 0; hh < 8; ++hh) { a += red1[hh][t]; b += red2[hh][t]; }
        atomicAdd(stats + t, a);
        atomicAdd(stats + D + t, b);
    }
}

__global__ void finalize_kernel(float* __restrict__ stats, const float* __restrict__ gamma,
                                const float* __restrict__ beta, float inv_rows)
{
    int c = threadIdx.x;  // 128
    float m = stats[c] * inv_rows;
    float v = stats[D + c] * inv_rows - m * m;
    float rstd = rsqrtf(v + BN_EPS);
    float sc = gamma[c] * rstd;
    stats[2 * D + c] = sc;
    stats[3 * D + c] = beta[c] - m * sc;
}

__global__ __launch_bounds__(256) void apply_h_kernel(
    float* __restrict__ h, const float* __restrict__ Th, const float* __restrict__ stats)
{
    int idx = blockIdx.x * 256 + threadIdx.x;
    int r = idx >> 5, d = (idx & 31) * 4;
    if (r >= NN) return;
    float4 tv = *(const float4*)(Th + (size_t)r * D + d);
    float4 sc = *(const float4*)(stats + 2 * D + d);
    float4 sh = *(const float4*)(stats + 3 * D + d);
    float4 hv = *(const float4*)(h + (size_t)r * D + d);
    hv.x += silu_(fmaf(tv.x, sc.x, sh.x));
    hv.y += silu_(fmaf(tv.y, sc.y, sh.y));
    hv.z += silu_(fmaf(tv.z, sc.z, sh.z));
    hv.w += silu_(fmaf(tv.w, sc.w, sh.w));
    *(float4*)(h + (size_t)r * D + d) = hv;
}

__global__ __launch_bounds__(256) void apply_e_kernel(
    unsigned short* __restrict__ e, const unsigned short* __restrict__ T,
    const float* __restrict__ stats)
{
    int idx = blockIdx.x * 256 + threadIdx.x;
    int r = idx >> 5, d = (idx & 31) * 4;
    if (r >= NE) return;
    ushort4 tv = *(const ushort4*)(T + (size_t)r * D + d);
    ushort4 ev = *(const ushort4*)(e + (size_t)r * D + d);
    float4 sc = *(const float4*)(stats + 2 * D + d);
    float4 sh = *(const float4*)(stats + 3 * D + d);
    ushort4 o;
    o.x = f2bf(bf2f(ev.x) + silu_(fmaf(bf2f(tv.x), sc.x, sh.x)));
    o.y = f2bf(bf2f(ev.y) + silu_(fmaf(bf2f(tv.y), sc.y, sh.y)));
    o.z = f2bf(bf2f(ev.z) + silu_(fmaf(bf2f(tv.z), sc.z, sh.z)));
    o.w = f2bf(bf2f(ev.w) + silu_(fmaf(bf2f(tv.w), sc.w, sh.w)));
    *(ushort4*)(e + (size_t)r * D + d) = o;
}

extern "C" void kernel_launch(void* const* d_in, const int* in_sizes, int n_in,
                              void* d_out, int out_size, void* d_ws, size_t ws_size,
                              hipStream_t stream)
{
    (void)in_sizes; (void)n_in; (void)out_size;
    const float* x = (const float*)d_in[0];
    const float* edge_attr = (const float*)d_in[1];
    const int* edge_index = (const int*)d_in[2];
    const int* src = edge_index;
    const int* dst = edge_index + NE;
    const float* hp_w = (const float*)d_in[3];
    const float* hp_b = (const float*)d_in[4];
    const float* ep_w = (const float*)d_in[5];
    const float* ep_b = (const float*)d_in[6];
    const float* Uw = (const float*)d_in[7];
    const float* Ub = (const float*)d_in[8];
    const float* Vw = (const float*)d_in[9];
    const float* Vb = (const float*)d_in[10];
    const float* Aw = (const float*)d_in[11];
    const float* Ab = (const float*)d_in[12];
    const float* Bw = (const float*)d_in[13];
    const float* Bb = (const float*)d_in[14];
    const float* Cw = (const float*)d_in[15];
    const float* Cb = (const float*)d_in[16];
    const float* h_gamma = (const float*)d_in[17];
    const float* h_beta = (const float*)d_in[18];
    const float* e_gamma = (const float*)d_in[19];
    const float* e_beta = (const float*)d_in[20];
    const float* f1w = (const float*)d_in[21];
    const float* f1b = (const float*)d_in[22];
    const float* f2w = (const float*)d_in[23];
    const float* f2b = (const float*)d_in[24];
    const float* f3w = (const float*)d_in[25];
    const float* f3b = (const float*)d_in[26];
    float* out = (float*)d_out;

    size_t off = 0;
    auto alloc = [&](size_t nbytes) {
        void* p = (char*)d_ws + off;
        off += ((nbytes + 255) / 256) * 256;
        return p;
    };
    unsigned short* e_bf = (unsigned short*)alloc((size_t)NE * D * 2);
    unsigned short* t_bf = (unsigned short*)alloc((size_t)NE * D * 2);
    float* h  = (float*)alloc((size_t)NN * D * 4);
    float* Uh = (float*)alloc((size_t)NN * D * 4);
    float* Vh = (float*)alloc((size_t)NN * D * 4);
    float* Bh = (float*)alloc((size_t)NN * D * 4);
    float* Ch = (float*)alloc((size_t)NN * D * 4);
    int* deg = (int*)alloc(NN * 4);
    int* rowptr = (int*)alloc((NN + 1) * 4);
    int* cursor = (int*)alloc(NN * 4);
    int* eidx = (int*)alloc((size_t)NE * 4);
    float* inv_cnt = (float*)alloc(NN * 4);
    float* statsH = (float*)alloc(4 * D * 4);
    float* statsE = (float*)alloc(4 * D * 4);
    unsigned short* wtA0 = (unsigned short*)alloc(D * D * 2);
    unsigned short* wtA1 = (unsigned short*)alloc(D * D * 2);
    unsigned short* wtA2 = (unsigned short*)alloc(D * D * 2);
    unsigned short* wtF1 = (unsigned short*)alloc(D * D * 2);
    unsigned short* wtF2 = (unsigned short*)alloc(D * D * 2);
    unsigned short* wtA[3] = {wtA0, wtA1, wtA2};

    if (off > ws_size) return;  // diagnostic guard

    const int nodeBlocks32 = (NN * 32 + 255) / 256;  // 2500
    const int edgeBlocks32 = (NE * 32) / 256;        // 40000
    const int nodeTiles = (NN + 127) / 128;          // 157
    const int edgeTiles = NE / 128;                  // 2500

    init_h_kernel<<<nodeBlocks32, 256, 0, stream>>>(x, hp_w, hp_b, h);
    init_e_kernel<<<edgeBlocks32, 256, 0, stream>>>(edge_attr, ep_w, ep_b, e_bf);

    // weight conversions (fp32 -> bf16 transposed)
    for (int l = 0; l < LAYERS; ++l)
        conv_wt_kernel<<<64, 256, 0, stream>>>(Aw + (size_t)l * D * D, wtA[l]);
    conv_wt_kernel<<<64, 256, 0, stream>>>(f1w, wtF1);
    conv_wt_kernel<<<64, 256, 0, stream>>>(f2w, wtF2);

    // CSR build
    hipMemsetAsync(deg, 0, NN * sizeof(int), stream);
    hipMemsetAsync(cursor, 0, NN * sizeof(int), stream);
    deg_kernel<<<NE / 256, 256, 0, stream>>>(src, deg);
    scan_kernel<<<1, 256, 0, stream>>>(deg, rowptr, inv_cnt);
    fill_kernel<<<NE / 256, 256, 0, stream>>>(src, rowptr, cursor, eidx);

    for (int l = 0; l < LAYERS; ++l) {
        const size_t wl = (size_t)l * D * D;
        const size_t bl = (size_t)l * D;

        Mats m4;
        m4.W[0] = Uw + wl; m4.W[1] = Vw + wl; m4.W[2] = Bw + wl; m4.W[3] = Cw + wl;
        m4.b[0] = Ub + bl; m4.b[1] = Vb + bl; m4.b[2] = Bb + bl; m4.b[3] = Cb + bl;
        m4.C[0] = Uh; m4.C[1] = Vh; m4.C[2] = Bh; m4.C[3] = Ch;
        mm_node_kernel<<<dim3(nodeTiles, 4), 256, 0, stream>>>(h, NN, m4);

        // Ae -> t_bf (bf16) via MFMA
        mfmm_edge_kernel<0><<<edgeTiles, 256, 0, stream>>>(e_bf, wtA[l], Ab + bl,
                                                           t_bf, nullptr, nullptr, nullptr);

        // gather-aggregate into Uh => t_h
        agg_kernel<<<(NN + 3) / 4, 256, 0, stream>>>(e_bf, Vh, rowptr, eidx, dst, inv_cnt, Uh);

        // h update
        hipMemsetAsync(statsH, 0, 2 * D * sizeof(float), stream);
        colstats_h_kernel<<<(NN + 1023) / 1024, 256, 0, stream>>>(Uh, statsH);
        finalize_kernel<<<1, D, 0, stream>>>(statsH, h_gamma + bl, h_beta + bl, 1.0f / NN);
        apply_h_kernel<<<nodeBlocks32, 256, 0, stream>>>(h, Uh, statsH);

        // e update
        hipMemsetAsync(statsE, 0, 2 * D * sizeof(float), stream);
        colstats_e_kernel<<<(NE + 1023) / 1024, 256, 0, stream>>>(t_bf, Bh, Ch, src, dst, statsE);
        finalize_kernel<<<1, D, 0, stream>>>(statsE, e_gamma + bl, e_beta + bl, 1.0f / NE);
        apply_e_kernel<<<edgeBlocks32, 256, 0, stream>>>(e_bf, t_bf, statsE);
    }

    // final MLP
    mfmm_edge_kernel<1><<<edgeTiles, 256, 0, stream>>>(e_bf, wtF1, f1b,
                                                       t_bf, nullptr, nullptr, nullptr);
    mfmm_edge_kernel<2><<<edgeTiles, 256, 0, stream>>>(t_bf, wtF2, f2b,
                                                       nullptr, f3w, f3b, out);
}